// Round 7
// baseline (425.538 us; speedup 1.0000x reference)
//
#include <hip/hip_runtime.h>
#include <hip/hip_bf16.h>

// CrossModalMDTA on gfx950 — round 7.
// Depthwise 3x3 fused into the projection GEMM epilogue (q0/kv0 eliminated):
// each block owns output row h of one group (q/k/v), computes conv1x1 for
// rows h-1,h,h+1 (3x redundant MFMA, L2-served B re-reads via XCD-chunk
// swizzle), stages each 1x1 row to LDS bf16 [px][ch], accumulates 9 taps
// into dwacc registers, writes one bf16 row + fp32 norm partials.

typedef __attribute__((ext_vector_type(8))) short short8;   // 8 x bf16
typedef __attribute__((ext_vector_type(4))) float f32x4;    // MFMA accum

static __device__ __forceinline__ float b2f(unsigned short u) {
    return __uint_as_float(((unsigned)u) << 16);
}
static __device__ __forceinline__ unsigned short f2b(float f) {
    unsigned u = __float_as_uint(f);
    u += 0x7FFFu + ((u >> 16) & 1u);          // RNE
    return (unsigned short)(u >> 16);
}
static __device__ __forceinline__ unsigned short f2bh(float f) {
    union { __hip_bfloat16 h; unsigned short u; } cv;
    cv.h = __float2bfloat16(f);
    return cv.u;
}

__global__ void cvt_f2b_kernel(const float* __restrict__ src,
                               unsigned short* __restrict__ dst, int n) {
    int i = blockIdx.x * blockDim.x + threadIdx.x;
    if (i < n) dst[i] = f2b(src[i]);
}

// ---------------------------------------------------------------------------
// proj_dw: grid (384 = 128h x 3groups swizzled, 1, 8 batches), 256 threads.
// Group y: 0 -> q (Wq, f_opt, norms->nq), 1 -> k (Wkv[0:192], f_sar, ->nk),
//          2 -> v (Wkv[192:384], f_sar, no norms).
// ---------------------------------------------------------------------------
__global__ void __launch_bounds__(256, 2) proj_dw(
    const unsigned short* __restrict__ wq_b,    // [192][192] bf16
    const unsigned short* __restrict__ wkv_b,   // [384][192] bf16
    const float* __restrict__ f_opt,
    const float* __restrict__ f_sar,
    const float* __restrict__ w_qdw,            // [192][9] fp32
    const float* __restrict__ w_kvdw,           // [384][9] fp32
    unsigned short* __restrict__ qbuf,          // [B][192][16384] bf16
    unsigned short* __restrict__ kvbuf,         // [B][384][16384] bf16
    float* __restrict__ nqPart,                 // [B][192][128]
    float* __restrict__ nkPart)                 // [B][192][128]
{
    constexpr long NPIX = 16384;
    const int bi  = blockIdx.x;                    // 0..383
    const int lid = (bi & 7) * 48 + (bi >> 3);     // XCD-chunk swizzle (bijective)
    const int h = lid / 3, y = lid - 3 * h;
    const int b = blockIdx.z;

    const unsigned short* A = (y == 0) ? wq_b : wkv_b + (size_t)(y - 1) * 192 * 192;
    const float* F   = ((y == 0) ? f_opt : f_sar) + (long)b * 192 * NPIX;
    const float* wdw = (y == 0) ? w_qdw : w_kvdw + (size_t)(y - 1) * 192 * 9;
    unsigned short* outp = (y == 0)
        ? qbuf + (long)b * 192 * NPIX
        : kvbuf + ((long)b * 384 + (long)(y - 1) * 192) * NPIX;

    const int tid  = threadIdx.x;
    const int wave = tid >> 6;
    const int lane = tid & 63;
    const int l15  = lane & 15;
    const int g    = lane >> 4;

    __shared__ unsigned short Bs[64][200];        // whole-K B staging, 25.6 KB
    __shared__ unsigned short OutRow[130][196];   // [px+2pad][ch+pad], 51.0 KB

    // zero the px pad rows (0 and 129); never rewritten
    if (tid < 98) {
        reinterpret_cast<unsigned*>(&OutRow[0][0])[tid]   = 0;
        reinterpret_cast<unsigned*>(&OutRow[129][0])[tid] = 0;
    }

    // dw ownership: 12 channels x 8 px per thread
    const int cBase = (tid >> 4) * 12;
    const int pBase = (tid & 15) * 8;

    float dwacc[12][8];
#pragma unroll
    for (int j = 0; j < 12; ++j)
#pragma unroll
        for (int p = 0; p < 8; ++p) dwacc[j][p] = 0.f;

    // staging ownership: 2 px x 24 k per thread
    const int px2 = (tid & 31) * 2;
    const int kg  = (tid >> 5) * 24;              // k range [kg, kg+24)

#pragma unroll 1
    for (int dr = -1; dr <= 1; ++dr) {
        const int r = h + dr;
        if (r < 0 || r > 127) continue;
        const float* Frow = F + (long)r * 128;

#pragma unroll 1
        for (int nh = 0; nh < 2; ++nh) {
            __syncthreads();   // Bs readers (prev half) + taps (prev row) done

            // ---- stage B: 192k x 64px fp32 -> bf16, transposed Bs[px][k]
            float va[24], vb[24];
#pragma unroll
            for (int j = 0; j < 24; ++j) {
                const float2 v = *reinterpret_cast<const float2*>(
                    Frow + (long)(kg + j) * NPIX + nh * 64 + px2);
                va[j] = v.x; vb[j] = v.y;
            }
            unsigned pa[12], pb[12];
#pragma unroll
            for (int t = 0; t < 12; ++t) {
                pa[t] = (unsigned)f2bh(va[2*t]) | ((unsigned)f2bh(va[2*t+1]) << 16);
                pb[t] = (unsigned)f2bh(vb[2*t]) | ((unsigned)f2bh(vb[2*t+1]) << 16);
            }
#pragma unroll
            for (int t = 0; t < 3; ++t) {
                uint4 qa = {pa[4*t], pa[4*t+1], pa[4*t+2], pa[4*t+3]};
                uint4 qb = {pb[4*t], pb[4*t+1], pb[4*t+2], pb[4*t+3]};
                *reinterpret_cast<uint4*>(&Bs[px2][kg + t*8])     = qa;
                *reinterpret_cast<uint4*>(&Bs[px2+1][kg + t*8])   = qb;
            }
            __syncthreads();

            // ---- GEMM: M=192 (4 waves x 48), N=64, K=192
            f32x4 acc[3][4];
#pragma unroll
            for (int i = 0; i < 3; ++i)
#pragma unroll
                for (int j = 0; j < 4; ++j) acc[i][j] = {0.f, 0.f, 0.f, 0.f};

#pragma unroll
            for (int s = 0; s < 6; ++s) {
                short8 af[3];
#pragma unroll
                for (int mt = 0; mt < 3; ++mt)
                    af[mt] = *reinterpret_cast<const short8*>(
                        A + (long)(wave * 48 + mt * 16 + l15) * 192 + s * 32 + g * 8);
                short8 bf[4];
#pragma unroll
                for (int nt = 0; nt < 4; ++nt)
                    bf[nt] = *reinterpret_cast<const short8*>(
                        &Bs[nt * 16 + l15][s * 32 + g * 8]);
#pragma unroll
                for (int nt = 0; nt < 4; ++nt)
#pragma unroll
                    for (int mt = 0; mt < 3; ++mt)
                        acc[mt][nt] = __builtin_amdgcn_mfma_f32_16x16x32_bf16(
                            af[mt], bf[nt], acc[mt][nt], 0, 0, 0);
            }

            // ---- acc -> OutRow bf16 (D row = g*4+r2, col = l15)
#pragma unroll
            for (int mt = 0; mt < 3; ++mt)
#pragma unroll
                for (int nt = 0; nt < 4; ++nt) {
                    const int px = nh * 64 + nt * 16 + l15;
                    const int ch = wave * 48 + mt * 16 + g * 4;
                    const unsigned lo = (unsigned)f2bh(acc[mt][nt][0])
                                      | ((unsigned)f2bh(acc[mt][nt][1]) << 16);
                    const unsigned hi = (unsigned)f2bh(acc[mt][nt][2])
                                      | ((unsigned)f2bh(acc[mt][nt][3]) << 16);
                    *reinterpret_cast<unsigned*>(&OutRow[px + 1][ch])     = lo;
                    *reinterpret_cast<unsigned*>(&OutRow[px + 1][ch + 2]) = hi;
                }
        }
        __syncthreads();   // OutRow complete for row r

        // ---- dw taps: source row r contributes with weight row (dr+1)
        float tw0[12], tw1[12], tw2[12];
#pragma unroll
        for (int j = 0; j < 12; ++j) {
            const float* wp = wdw + (cBase + j) * 9 + (dr + 1) * 3;
            tw0[j] = wp[0]; tw1[j] = wp[1]; tw2[j] = wp[2];
        }
#pragma unroll
        for (int w = 0; w < 10; ++w) {          // padded px rows pBase..pBase+9
            float v[12];
#pragma unroll
            for (int t = 0; t < 3; ++t) {
                const uint2 u = *reinterpret_cast<const uint2*>(
                    &OutRow[pBase + w][cBase + 4 * t]);
                v[4*t+0] = b2f((unsigned short)(u.x & 0xFFFF));
                v[4*t+1] = b2f((unsigned short)(u.x >> 16));
                v[4*t+2] = b2f((unsigned short)(u.y & 0xFFFF));
                v[4*t+3] = b2f((unsigned short)(u.y >> 16));
            }
            const int pw = w - 1;               // real px offset rel. pBase
#pragma unroll
            for (int j = 0; j < 12; ++j) {
                if (pw - 1 >= 0 && pw - 1 < 8) dwacc[j][pw - 1] += tw2[j] * v[j];
                if (pw     >= 0 && pw     < 8) dwacc[j][pw]     += tw1[j] * v[j];
                if (pw + 1 >= 0 && pw + 1 < 8) dwacc[j][pw + 1] += tw0[j] * v[j];
            }
        }
    }

    // ---- store dw output row h (bf16) + norm partials
#pragma unroll
    for (int j = 0; j < 12; ++j) {
        short8 o;
#pragma unroll
        for (int p = 0; p < 8; ++p) o[p] = (short)f2b(dwacc[j][p]);
        *reinterpret_cast<short8*>(
            outp + (long)(cBase + j) * NPIX + h * 128 + pBase) = o;
    }
    if (y < 2) {
        float* np = ((y == 0) ? nqPart : nkPart) + (long)b * 192 * 128;
#pragma unroll
        for (int j = 0; j < 12; ++j) {
            float s = 0.f;
#pragma unroll
            for (int p = 0; p < 8; ++p) s += dwacc[j][p] * dwacc[j][p];
            s += __shfl_xor(s, 1); s += __shfl_xor(s, 2);
            s += __shfl_xor(s, 4); s += __shfl_xor(s, 8);
            if (l15 == 0) np[(long)(cBase + j) * 128 + h] = s;
        }
    }
}

// ---------------------------------------------------------------------------
// final GEMM: out = M_b @ v  (round-6 split-K double-buffered body, BN=128)
// ---------------------------------------------------------------------------
__global__ void __launch_bounds__(256) final_gemm(
    const unsigned short* __restrict__ Mmat,   // [B,192,192] bf16
    const unsigned short* __restrict__ vsrc,   // v rows, stride vStride per b
    float* __restrict__ out, long vStride)
{
    constexpr long N = 16384;
    constexpr int K = 192;
    const int b = blockIdx.z;
    const unsigned short* A = Mmat + (long)b * 192 * 192;
    const unsigned short* B = vsrc + (long)b * vStride;
    float* C = out + (long)b * 192 * N;

    const int tid  = threadIdx.x;
    const int wave = tid >> 6;
    const int lane = tid & 63;
    const int l15  = lane & 15;
    const int g    = lane >> 4;
    const long n0  = (long)blockIdx.x * 128;

    __shared__ unsigned short Bs[2][128][72];

    const int nc = tid & 127;
    const int kb = tid >> 7;

    unsigned short sv[4][8];
    auto load_regs = [&](int s) {
#pragma unroll
        for (int i = 0; i < 4; ++i) {
            const int kc = kb + 2 * i;
            const unsigned short* bp = B + (long)(s * 64 + kc * 8) * N + n0 + nc;
#pragma unroll
            for (int j = 0; j < 8; ++j) sv[i][j] = bp[j * N];
        }
    };
    auto write_lds = [&](int buf) {
#pragma unroll
        for (int i = 0; i < 4; ++i) {
            const int kc = kb + 2 * i;
            unsigned w[4];
#pragma unroll
            for (int t = 0; t < 4; ++t)
                w[t] = (unsigned)sv[i][2*t] | ((unsigned)sv[i][2*t+1] << 16);
            uint4 pk = {w[0], w[1], w[2], w[3]};
            *reinterpret_cast<uint4*>(&Bs[buf][nc][kc * 8]) = pk;
        }
    };

    f32x4 acc[3][8];
#pragma unroll
    for (int i = 0; i < 3; ++i)
#pragma unroll
        for (int j = 0; j < 8; ++j) acc[i][j] = {0.f, 0.f, 0.f, 0.f};

    load_regs(0);
    write_lds(0);
    __syncthreads();

#pragma unroll
    for (int s = 0; s < 3; ++s) {
        const int buf = s & 1;
        if (s < 2) load_regs(s + 1);
#pragma unroll
        for (int s32 = 0; s32 < 2; ++s32) {
            short8 af[3];
#pragma unroll
            for (int mt = 0; mt < 3; ++mt)
                af[mt] = *reinterpret_cast<const short8*>(
                    A + (long)(wave * 48 + mt * 16 + l15) * K + s * 64 + s32 * 32 + g * 8);
            short8 bf[8];
#pragma unroll
            for (int nt = 0; nt < 8; ++nt)
                bf[nt] = *reinterpret_cast<const short8*>(
                    &Bs[buf][nt * 16 + l15][s32 * 32 + g * 8]);
#pragma unroll
            for (int nt = 0; nt < 8; ++nt)
#pragma unroll
                for (int mt = 0; mt < 3; ++mt)
                    acc[mt][nt] = __builtin_amdgcn_mfma_f32_16x16x32_bf16(
                        af[mt], bf[nt], acc[mt][nt], 0, 0, 0);
        }
        if (s < 2) {
            write_lds(buf ^ 1);
            __syncthreads();
        }
    }

#pragma unroll
    for (int mt = 0; mt < 3; ++mt)
#pragma unroll
        for (int nt = 0; nt < 8; ++nt) {
            const int row = wave * 48 + mt * 16 + g * 4;
            const long col = n0 + nt * 16 + l15;
#pragma unroll
            for (int r = 0; r < 4; ++r)
                C[(long)(row + r) * N + col] = acc[mt][nt][r];
        }
}

// ---------------------------------------------------------------------------
// Gram: G[d,e] = sum_n q[d,n]*k[e,n] per (b,h), N chunked into 16 x 1024.
// ---------------------------------------------------------------------------
__global__ void __launch_bounds__(256) gram_kernel(
    const unsigned short* __restrict__ q,    // [B,192,N] bf16
    const unsigned short* __restrict__ kv,   // [B,384,N] bf16 (k = first 192)
    float* __restrict__ Gpart)               // [B,4,16,2304]
{
    constexpr long N = 16384;
    const int chunk = blockIdx.x, h = blockIdx.y, b = blockIdx.z;
    const int tid = threadIdx.x;
    const int wave = tid >> 6, lane = tid & 63;
    const int l15 = lane & 15, g = lane >> 4;
    const unsigned short* qp = q  + ((long)b * 192 + h * 48) * N;
    const unsigned short* kp = kv + ((long)b * 384 + h * 48) * N;
    const int nbase = chunk * 1024 + wave * 256;

    f32x4 acc[3][3];
#pragma unroll
    for (int i = 0; i < 3; ++i)
#pragma unroll
        for (int j = 0; j < 3; ++j) acc[i][j] = {0.f, 0.f, 0.f, 0.f};

    for (int s = 0; s < 8; ++s) {
        const long n0 = nbase + s * 32 + g * 8;
        short8 af[3], bf[3];
#pragma unroll
        for (int mt = 0; mt < 3; ++mt)
            af[mt] = *reinterpret_cast<const short8*>(qp + (long)(mt*16 + l15) * N + n0);
#pragma unroll
        for (int nt = 0; nt < 3; ++nt)
            bf[nt] = *reinterpret_cast<const short8*>(kp + (long)(nt*16 + l15) * N + n0);
#pragma unroll
        for (int mt = 0; mt < 3; ++mt)
#pragma unroll
            for (int nt = 0; nt < 3; ++nt)
                acc[mt][nt] = __builtin_amdgcn_mfma_f32_16x16x32_bf16(
                    af[mt], bf[nt], acc[mt][nt], 0, 0, 0);
    }

    __shared__ float Gt[4][2304];
#pragma unroll
    for (int mt = 0; mt < 3; ++mt)
#pragma unroll
        for (int nt = 0; nt < 3; ++nt)
#pragma unroll
            for (int r = 0; r < 4; ++r)
                Gt[wave][(mt*16 + g*4 + r) * 48 + nt*16 + l15] = acc[mt][nt][r];
    __syncthreads();

    float* gout = Gpart + (((long)(b * 4 + h)) * 16 + chunk) * 2304;
    for (int i = tid; i < 2304; i += 256)
        gout[i] = Gt[0][i] + Gt[1][i] + Gt[2][i] + Gt[3][i];
}

// ---------------------------------------------------------------------------
// Per (b,h): reduce partials, softmax(G/(nq*nk)*T), fold w_out:
// M[c, 48h+e] = sum_d w_out[c, 48h+d] * attn[d,e]
// ---------------------------------------------------------------------------
__global__ void __launch_bounds__(256) attn_m_kernel(
    const float* __restrict__ Gpart,        // [B,4,16,2304]
    const float* __restrict__ nqPart,       // [B,192,128]
    const float* __restrict__ nkPart,       // [B,192,128]
    const float* __restrict__ w_out,        // [192,192] fp32
    const float* __restrict__ temperature,  // [4]
    unsigned short* __restrict__ Mmat)      // [B,192,192] bf16
{
    const int blk = blockIdx.x;
    const int b = blk >> 2, h = blk & 3;
    const int tid = threadIdx.x;
    __shared__ float G[2304];
    __shared__ float At[2304];
    __shared__ float nqv[48], nkv[48];

    const long base = ((long)(b * 4 + h)) * 16;
    for (int i = tid; i < 2304; i += 256) {
        float s = 0.f;
        for (int c = 0; c < 16; ++c) s += Gpart[(base + c) * 2304 + i];
        G[i] = s;
    }
    if (tid < 96) {
        const int isK = tid >= 48;
        const int d = tid - 48 * isK;
        const float* p = (isK ? nkPart : nqPart) + ((long)b * 192 + h * 48 + d) * 128;
        float s = 0.f;
        for (int i = 0; i < 128; ++i) s += p[i];
        const float nrm = fmaxf(sqrtf(s), 1e-12f);
        if (isK) nkv[d] = nrm; else nqv[d] = nrm;
    }
    __syncthreads();

    const float T = temperature[h];
    if (tid < 48) {
        const int d = tid;
        const float scale = T / nqv[d];
        float m = -1e30f;
        for (int e = 0; e < 48; ++e) {
            const float sv = G[d * 48 + e] * scale / nkv[e];
            At[d * 48 + e] = sv;
            m = fmaxf(m, sv);
        }
        float sum = 0.f;
        for (int e = 0; e < 48; ++e) {
            const float ex = expf(At[d * 48 + e] - m);
            At[d * 48 + e] = ex;
            sum += ex;
        }
        const float inv = 1.f / sum;
        for (int e = 0; e < 48; ++e) At[d * 48 + e] *= inv;
    }
    __syncthreads();

    for (int i = tid; i < 192 * 48; i += 256) {
        const int c = i / 48, e = i - (i / 48) * 48;
        const float* wrow = w_out + (long)c * 192 + h * 48;
        float s = 0.f;
        for (int d = 0; d < 48; ++d) s += wrow[d] * At[d * 48 + e];
        Mmat[((long)b * 192 + c) * 192 + h * 48 + e] = f2b(s);
    }
}

// ---------------------------------------------------------------------------
extern "C" void kernel_launch(void* const* d_in, const int* in_sizes, int n_in,
                              void* d_out, int out_size, void* d_ws, size_t ws_size,
                              hipStream_t stream)
{
    const float* f_opt  = (const float*)d_in[0];
    const float* f_sar  = (const float*)d_in[1];
    const float* w_q    = (const float*)d_in[2];
    const float* w_qdw  = (const float*)d_in[3];
    const float* w_kv   = (const float*)d_in[4];
    const float* w_kvdw = (const float*)d_in[5];
    const float* w_out  = (const float*)d_in[6];
    const float* temper = (const float*)d_in[7];
    float* out = (float*)d_out;

    const long N = 16384;
    char* ws = (char*)d_ws;
    size_t off = 0;
    auto alloc = [&](size_t bytes) -> void* {
        void* p = ws + off;
        off = (off + bytes + 255) & ~(size_t)255;
        return p;
    };

    unsigned short* wq_b  = (unsigned short*)alloc((size_t)192 * 192 * 2);
    unsigned short* wkv_b = (unsigned short*)alloc((size_t)384 * 192 * 2);
    unsigned short* Mmat  = (unsigned short*)alloc((size_t)8 * 192 * 192 * 2);
    float* Gpart  = (float*)alloc((size_t)8 * 4 * 16 * 2304 * 4);
    float* nqPart = (float*)alloc((size_t)8 * 192 * 128 * 4);
    float* nkPart = (float*)alloc((size_t)8 * 192 * 128 * 4);
    unsigned short* qbuf  = (unsigned short*)alloc((size_t)8 * 192 * N * 2);
    unsigned short* kvbuf = (unsigned short*)alloc((size_t)8 * 384 * N * 2);

    cvt_f2b_kernel<<<dim3((192*192 + 255) / 256), 256, 0, stream>>>(w_q,  wq_b,  192*192);
    cvt_f2b_kernel<<<dim3((384*192 + 255) / 256), 256, 0, stream>>>(w_kv, wkv_b, 384*192);

    proj_dw<<<dim3(384, 1, 8), 256, 0, stream>>>(
        wq_b, wkv_b, f_opt, f_sar, w_qdw, w_kvdw,
        qbuf, kvbuf, nqPart, nkPart);

    gram_kernel<<<dim3(16, 4, 8), 256, 0, stream>>>(qbuf, kvbuf, Gpart);
    attn_m_kernel<<<dim3(32), 256, 0, stream>>>(Gpart, nqPart, nkPart, w_out, temper, Mmat);

    // out = M_b @ v  (v = channels 192..383 of kvbuf)
    final_gemm<<<dim3(128, 1, 8), 256, 0, stream>>>(
        Mmat, kvbuf + 192 * N, out, 384 * N);
}

// Round 8
// 276.184 us; speedup vs baseline: 1.5408x; 1.5408x over previous
//
#include <hip/hip_runtime.h>
#include <hip/hip_bf16.h>

// CrossModalMDTA on gfx950 — round 8.
// Round-6 structure (best so far: proj split-K dbuf GEMM + separate dw pass).
// dw3x3_all halo loads replaced by lane shuffles: 3 coalesced short8 reads +
// 2 shfl per row instead of 6 scalar 2B edge loads -> 3x fewer HBM requests.

typedef __attribute__((ext_vector_type(8))) short short8;   // 8 x bf16
typedef __attribute__((ext_vector_type(4))) float f32x4;    // MFMA accum

static __device__ __forceinline__ float b2f(unsigned short u) {
    return __uint_as_float(((unsigned)u) << 16);
}
static __device__ __forceinline__ unsigned short f2b(float f) {
    unsigned u = __float_as_uint(f);
    u += 0x7FFFu + ((u >> 16) & 1u);          // RNE
    return (unsigned short)(u >> 16);
}
static __device__ __forceinline__ unsigned short f2bh(float f) {
    union { __hip_bfloat16 h; unsigned short u; } cv;
    cv.h = __float2bfloat16(f);
    return cv.u;
}

__global__ void cvt_f2b_kernel(const float* __restrict__ src,
                               unsigned short* __restrict__ dst, int n) {
    int i = blockIdx.x * blockDim.x + threadIdx.x;
    if (i < n) dst[i] = f2b(src[i]);
}

// ---------------------------------------------------------------------------
// GEMM body: C[m,n] = sum_k A[m,k]*B[k,n], K=192, N=16384, M=192.
// Block = 4 waves, tile 192m x 128n. K split into 3 stages of 64, double-
// buffered: per stage, next-stage global loads issue before this stage's MFMA.
// ---------------------------------------------------------------------------
template<typename Bty, typename Oty>
static __device__ __forceinline__ void gemm_body(
    const unsigned short* __restrict__ A,   // bf16 [192 x 192]
    const Bty* __restrict__ B,              // [192 x N] fp32 or bf16
    Oty* __restrict__ C)                    // [192 x N] bf16(ushort) or fp32
{
    constexpr long N = 16384;
    constexpr int K = 192;
    const int tid  = threadIdx.x;
    const int wave = tid >> 6;
    const int lane = tid & 63;
    const int l15  = lane & 15;
    const int g    = lane >> 4;
    const long n0  = (long)blockIdx.x * 128;

    __shared__ unsigned short Bs[2][128][72];   // 36.9 KB, rows 144B (16B-mult)

    const int nc = tid & 127;       // n column
    const int kb = tid >> 7;        // 0..1 (k-chunk parity)

    float fv[4][8];
    unsigned short sv[4][8];

    auto load_regs = [&](int s) {
#pragma unroll
        for (int i = 0; i < 4; ++i) {
            const int kc = kb + 2 * i;              // local k-chunk 0..7
            const Bty* bp = B + (long)(s * 64 + kc * 8) * N + n0 + nc;
#pragma unroll
            for (int j = 0; j < 8; ++j) {
                if constexpr (sizeof(Bty) == 4) fv[i][j] = (float)bp[j * N];
                else                            sv[i][j] = bp[j * N];
            }
        }
    };
    auto write_lds = [&](int buf) {
#pragma unroll
        for (int i = 0; i < 4; ++i) {
            const int kc = kb + 2 * i;
            unsigned w[4];
#pragma unroll
            for (int t = 0; t < 4; ++t) {
                if constexpr (sizeof(Bty) == 4)
                    w[t] = (unsigned)f2bh(fv[i][2*t]) | ((unsigned)f2bh(fv[i][2*t+1]) << 16);
                else
                    w[t] = (unsigned)sv[i][2*t] | ((unsigned)sv[i][2*t+1] << 16);
            }
            uint4 pk = {w[0], w[1], w[2], w[3]};
            *reinterpret_cast<uint4*>(&Bs[buf][nc][kc * 8]) = pk;
        }
    };

    f32x4 acc[3][8];
#pragma unroll
    for (int i = 0; i < 3; ++i)
#pragma unroll
        for (int j = 0; j < 8; ++j) acc[i][j] = {0.f, 0.f, 0.f, 0.f};

    load_regs(0);
    write_lds(0);
    __syncthreads();

#pragma unroll
    for (int s = 0; s < 3; ++s) {
        const int buf = s & 1;
        if (s < 2) load_regs(s + 1);        // overlap with MFMA below
#pragma unroll
        for (int s32 = 0; s32 < 2; ++s32) {
            short8 af[3];
#pragma unroll
            for (int mt = 0; mt < 3; ++mt)
                af[mt] = *reinterpret_cast<const short8*>(
                    A + (long)(wave * 48 + mt * 16 + l15) * K + s * 64 + s32 * 32 + g * 8);
            short8 bf[8];
#pragma unroll
            for (int nt = 0; nt < 8; ++nt)
                bf[nt] = *reinterpret_cast<const short8*>(
                    &Bs[buf][nt * 16 + l15][s32 * 32 + g * 8]);
#pragma unroll
            for (int nt = 0; nt < 8; ++nt)
#pragma unroll
                for (int mt = 0; mt < 3; ++mt)
                    acc[mt][nt] = __builtin_amdgcn_mfma_f32_16x16x32_bf16(
                        af[mt], bf[nt], acc[mt][nt], 0, 0, 0);
        }
        if (s < 2) {
            write_lds(buf ^ 1);             // other buffer: safe concurrently
            __syncthreads();
        }
    }

    // epilogue: D row = (lane>>4)*4 + r, col = lane&15
#pragma unroll
    for (int mt = 0; mt < 3; ++mt) {
#pragma unroll
        for (int nt = 0; nt < 8; ++nt) {
            const int row = wave * 48 + mt * 16 + g * 4;
            const long col = n0 + nt * 16 + l15;
#pragma unroll
            for (int r = 0; r < 4; ++r) {
                const float v = acc[mt][nt][r];
                if constexpr (sizeof(Oty) == 4)
                    C[(long)(row + r) * N + col] = v;
                else
                    C[(long)(row + r) * N + col] = f2b(v);
            }
        }
    }
}

// fused q + kv projection: y==0 -> q0 = Wq*f_opt ; y==1,2 -> kv0 halves
__global__ void __launch_bounds__(256) proj_gemm(
    const unsigned short* __restrict__ wq_b,   // [192x192] bf16
    const unsigned short* __restrict__ wkv_b,  // [384x192] bf16
    const float* __restrict__ f_opt,
    const float* __restrict__ f_sar,
    unsigned short* __restrict__ q0,
    unsigned short* __restrict__ kv0,
    long q0S, long kv0S, int batch0)
{
    constexpr long N = 16384;
    const int b = batch0 + blockIdx.z;
    const int y = blockIdx.y;
    if (y == 0) {
        gemm_body<float, unsigned short>(
            wq_b, f_opt + (long)b * 192 * N, q0 + (long)b * q0S);
    } else {
        gemm_body<float, unsigned short>(
            wkv_b + (long)(y - 1) * 192 * 192,
            f_sar + (long)b * 192 * N,
            kv0 + (long)b * kv0S + (long)(y - 1) * 192 * N);
    }
}

// final: out = M_b @ v
__global__ void __launch_bounds__(256) final_gemm(
    const unsigned short* __restrict__ Mmat,   // [B,192,192] bf16
    const unsigned short* __restrict__ v,      // v rows, stride vStride per b
    float* __restrict__ out, long vStride)
{
    constexpr long N = 16384;
    const int b = blockIdx.z;
    gemm_body<unsigned short, float>(
        Mmat + (long)b * 192 * 192, v + (long)b * vStride, out + (long)b * 192 * N);
}

// ---------------------------------------------------------------------------
// depthwise 3x3 (SAME, zero pad), bf16 in/out, fp32 accum — q and kv merged.
// Halo via lane shuffles: lanes 0..15 of each 16-lane group cover one full
// 128-px image row, so r[0]/r[9] come from neighbor lanes (0 at true edges).
// ---------------------------------------------------------------------------
__global__ void __launch_bounds__(256) dw3x3_all(
    const unsigned short* __restrict__ q0,
    const unsigned short* __restrict__ kv0,
    unsigned short* __restrict__ qbuf,
    unsigned short* __restrict__ kvbuf,
    const float* __restrict__ w_qdw,        // [192][9]
    const float* __restrict__ w_kvdw,       // [384][9]
    float* __restrict__ nqPart,             // [B][192][32]
    float* __restrict__ nkPart,             // [B][192][32]
    long q0S, long kv0S, int batch0)
{
    const int b  = batch0 + blockIdx.z;
    const int t  = blockIdx.x * 256 + threadIdx.x;
    const int l16 = threadIdx.x & 15;        // == t & 15
    const int w0 = l16 * 8;
    const int hh = (t >> 4) & 127;
    const int c_all = t >> 11;               // 0..575
    if (c_all >= 576) return;

    const unsigned short* s;
    unsigned short* d;
    const float* wp;
    if (c_all < 192) {
        s  = q0 + (long)b * q0S + ((long)c_all << 14);
        d  = qbuf + ((long)b * 192 + c_all) * 16384;
        wp = w_qdw + c_all * 9;
    } else {
        const int c = c_all - 192;
        s  = kv0 + (long)b * kv0S + ((long)c << 14);
        d  = kvbuf + ((long)b * 384 + c) * 16384;
        wp = w_kvdw + c * 9;
    }

    float wt[9];
#pragma unroll
    for (int i = 0; i < 9; ++i) wt[i] = wp[i];

    float acc[8] = {0, 0, 0, 0, 0, 0, 0, 0};
#pragma unroll
    for (int dy = 0; dy < 3; ++dy) {
        const int hy = hh + dy - 1;
        if (hy < 0 || hy > 127) continue;
        const unsigned short* row = s + hy * 128 + w0;
        float r[10];
        const short8 v = *reinterpret_cast<const short8*>(row);
#pragma unroll
        for (int i = 0; i < 8; ++i) r[i + 1] = b2f((unsigned short)v[i]);
        // halo from neighbor lanes (same image row within 16-lane group)
        const float left  = __shfl_up(r[8], 1);
        const float right = __shfl_down(r[1], 1);
        r[0] = (l16 > 0)  ? left  : 0.f;
        r[9] = (l16 < 15) ? right : 0.f;
#pragma unroll
        for (int j = 0; j < 8; ++j)
            acc[j] += wt[dy*3+0]*r[j] + wt[dy*3+1]*r[j+1] + wt[dy*3+2]*r[j+2];
    }

    short8 o;
#pragma unroll
    for (int j = 0; j < 8; ++j) o[j] = (short)f2b(acc[j]);
    *reinterpret_cast<short8*>(d + hh * 128 + w0) = o;

    float* np = nullptr;
    if (c_all < 192)      np = nqPart + ((long)b * 192 + c_all) * 32;
    else if (c_all < 384) np = nkPart + ((long)b * 192 + (c_all - 192)) * 32;
    if (np) {
        float ssq = 0.f;
#pragma unroll
        for (int j = 0; j < 8; ++j) ssq += acc[j] * acc[j];
#pragma unroll
        for (int ofs = 1; ofs < 64; ofs <<= 1) ssq += __shfl_xor(ssq, ofs);
        if ((threadIdx.x & 63) == 0) np[(t & 2047) >> 6] = ssq;
    }
}

// ---------------------------------------------------------------------------
// Gram: G[d,e] = sum_n q[d,n]*k[e,n] per (b,h), N chunked into 16 x 1024.
// ---------------------------------------------------------------------------
__global__ void __launch_bounds__(256) gram_kernel(
    const unsigned short* __restrict__ q,    // [B,192,N] bf16
    const unsigned short* __restrict__ kv,   // [B,384,N] bf16 (k = first 192)
    float* __restrict__ Gpart)               // [B,4,16,2304]
{
    constexpr long N = 16384;
    const int chunk = blockIdx.x, h = blockIdx.y, b = blockIdx.z;
    const int tid = threadIdx.x;
    const int wave = tid >> 6, lane = tid & 63;
    const int l15 = lane & 15, g = lane >> 4;
    const unsigned short* qp = q  + ((long)b * 192 + h * 48) * N;
    const unsigned short* kp = kv + ((long)b * 384 + h * 48) * N;
    const int nbase = chunk * 1024 + wave * 256;

    f32x4 acc[3][3];
#pragma unroll
    for (int i = 0; i < 3; ++i)
#pragma unroll
        for (int j = 0; j < 3; ++j) acc[i][j] = {0.f, 0.f, 0.f, 0.f};

    for (int s = 0; s < 8; ++s) {
        const long n0 = nbase + s * 32 + g * 8;
        short8 af[3], bf[3];
#pragma unroll
        for (int mt = 0; mt < 3; ++mt)
            af[mt] = *reinterpret_cast<const short8*>(qp + (long)(mt*16 + l15) * N + n0);
#pragma unroll
        for (int nt = 0; nt < 3; ++nt)
            bf[nt] = *reinterpret_cast<const short8*>(kp + (long)(nt*16 + l15) * N + n0);
#pragma unroll
        for (int mt = 0; mt < 3; ++mt)
#pragma unroll
            for (int nt = 0; nt < 3; ++nt)
                acc[mt][nt] = __builtin_amdgcn_mfma_f32_16x16x32_bf16(
                    af[mt], bf[nt], acc[mt][nt], 0, 0, 0);
    }

    __shared__ float Gt[4][2304];
#pragma unroll
    for (int mt = 0; mt < 3; ++mt)
#pragma unroll
        for (int nt = 0; nt < 3; ++nt)
#pragma unroll
            for (int r = 0; r < 4; ++r)
                Gt[wave][(mt*16 + g*4 + r) * 48 + nt*16 + l15] = acc[mt][nt][r];
    __syncthreads();

    float* gout = Gpart + (((long)(b * 4 + h)) * 16 + chunk) * 2304;
    for (int i = tid; i < 2304; i += 256)
        gout[i] = Gt[0][i] + Gt[1][i] + Gt[2][i] + Gt[3][i];
}

// ---------------------------------------------------------------------------
// Per (b,h): reduce partials, softmax(G/(nq*nk)*T), fold w_out:
// M[c, 48h+e] = sum_d w_out[c, 48h+d] * attn[d,e]
// ---------------------------------------------------------------------------
__global__ void __launch_bounds__(256) attn_m_kernel(
    const float* __restrict__ Gpart,        // [B,4,16,2304]
    const float* __restrict__ nqPart,       // [B,192,32]
    const float* __restrict__ nkPart,       // [B,192,32]
    const float* __restrict__ w_out,        // [192,192] fp32
    const float* __restrict__ temperature,  // [4]
    unsigned short* __restrict__ Mmat)      // [B,192,192] bf16
{
    const int blk = blockIdx.x;
    const int b = blk >> 2, h = blk & 3;
    const int tid = threadIdx.x;
    __shared__ float G[2304];
    __shared__ float At[2304];
    __shared__ float nqv[48], nkv[48];

    const long base = ((long)(b * 4 + h)) * 16;
    for (int i = tid; i < 2304; i += 256) {
        float s = 0.f;
        for (int c = 0; c < 16; ++c) s += Gpart[(base + c) * 2304 + i];
        G[i] = s;
    }
    if (tid < 96) {
        const int isK = tid >= 48;
        const int d = tid - 48 * isK;
        const float* p = (isK ? nkPart : nqPart) + ((long)b * 192 + h * 48 + d) * 32;
        float s = 0.f;
        for (int i = 0; i < 32; ++i) s += p[i];
        const float nrm = fmaxf(sqrtf(s), 1e-12f);
        if (isK) nkv[d] = nrm; else nqv[d] = nrm;
    }
    __syncthreads();

    const float T = temperature[h];
    if (tid < 48) {
        const int d = tid;
        const float scale = T / nqv[d];
        float m = -1e30f;
        for (int e = 0; e < 48; ++e) {
            const float sv = G[d * 48 + e] * scale / nkv[e];
            At[d * 48 + e] = sv;
            m = fmaxf(m, sv);
        }
        float sum = 0.f;
        for (int e = 0; e < 48; ++e) {
            const float ex = expf(At[d * 48 + e] - m);
            At[d * 48 + e] = ex;
            sum += ex;
        }
        const float inv = 1.f / sum;
        for (int e = 0; e < 48; ++e) At[d * 48 + e] *= inv;
    }
    __syncthreads();

    for (int i = tid; i < 192 * 48; i += 256) {
        const int c = i / 48, e = i - (i / 48) * 48;
        const float* wrow = w_out + (long)c * 192 + h * 48;
        float s = 0.f;
        for (int d = 0; d < 48; ++d) s += wrow[d] * At[d * 48 + e];
        Mmat[((long)b * 192 + c) * 192 + h * 48 + e] = f2b(s);
    }
}

// ---------------------------------------------------------------------------
extern "C" void kernel_launch(void* const* d_in, const int* in_sizes, int n_in,
                              void* d_out, int out_size, void* d_ws, size_t ws_size,
                              hipStream_t stream)
{
    const float* f_opt  = (const float*)d_in[0];
    const float* f_sar  = (const float*)d_in[1];
    const float* w_q    = (const float*)d_in[2];
    const float* w_qdw  = (const float*)d_in[3];
    const float* w_kv   = (const float*)d_in[4];
    const float* w_kvdw = (const float*)d_in[5];
    const float* w_out  = (const float*)d_in[6];
    const float* temper = (const float*)d_in[7];
    float* out = (float*)d_out;

    const long N = 16384;
    char* ws = (char*)d_ws;
    size_t off = 0;
    auto alloc = [&](size_t bytes) -> void* {
        void* p = ws + off;
        off = (off + bytes + 255) & ~(size_t)255;
        return p;
    };

    unsigned short* wq_b  = (unsigned short*)alloc((size_t)192 * 192 * 2);
    unsigned short* wkv_b = (unsigned short*)alloc((size_t)384 * 192 * 2);
    unsigned short* Mmat  = (unsigned short*)alloc((size_t)8 * 192 * 192 * 2);
    float* Gpart  = (float*)alloc((size_t)8 * 4 * 16 * 2304 * 4);
    float* nqPart = (float*)alloc((size_t)8 * 192 * 32 * 4);
    float* nkPart = (float*)alloc((size_t)8 * 192 * 32 * 4);
    unsigned short* qbuf  = (unsigned short*)alloc((size_t)8 * 192 * N * 2);
    unsigned short* kvbuf = (unsigned short*)alloc((size_t)8 * 384 * N * 2);

    const size_t fullNeed = off + ((size_t)8 * 192 * N * 2 + 256)
                                + ((size_t)8 * 384 * N * 2 + 256);
    const bool full = (ws_size >= fullNeed);

    unsigned short *q0, *kv0;
    long q0S, kv0S; int nz;
    if (full) {
        q0  = (unsigned short*)alloc((size_t)8 * 192 * N * 2);
        kv0 = (unsigned short*)alloc((size_t)8 * 384 * N * 2);
        q0S = 192 * N; kv0S = 384 * N; nz = 8;
    } else {
        q0  = (unsigned short*)alloc((size_t)192 * N * 2);
        kv0 = (unsigned short*)alloc((size_t)384 * N * 2);
        q0S = 0; kv0S = 0; nz = 1;
    }

    cvt_f2b_kernel<<<dim3((192*192 + 255) / 256), 256, 0, stream>>>(w_q,  wq_b,  192*192);
    cvt_f2b_kernel<<<dim3((384*192 + 255) / 256), 256, 0, stream>>>(w_kv, wkv_b, 384*192);

    const int iters = full ? 1 : 8;
    for (int it = 0; it < iters; ++it) {
        const int b0 = full ? 0 : it;
        proj_gemm<<<dim3(128, 3, nz), 256, 0, stream>>>(
            wq_b, wkv_b, f_opt, f_sar, q0, kv0, q0S, kv0S, b0);
        dw3x3_all<<<dim3(4608, 1, nz), 256, 0, stream>>>(
            q0, kv0, qbuf, kvbuf, w_qdw, w_kvdw, nqPart, nkPart, q0S, kv0S, b0);
    }

    gram_kernel<<<dim3(16, 4, 8), 256, 0, stream>>>(qbuf, kvbuf, Gpart);
    attn_m_kernel<<<dim3(32), 256, 0, stream>>>(Gpart, nqPart, nkPart, w_out, temper, Mmat);

    // out = M_b @ v  (v = channels 192..383 of kv)
    final_gemm<<<dim3(128, 1, 8), 256, 0, stream>>>(
        Mmat, kvbuf + 192 * N, out, 384 * N);
}